// Round 4
// baseline (396.551 us; speedup 1.0000x reference)
//
#include <hip/hip_runtime.h>
#include <hip/hip_bf16.h>

typedef unsigned short u16;
typedef unsigned int u32;

#define N_NODES 50000
#define N_EDGES 800000
#define DHID 256
#define NCHUNK 49  // ceil(50000/1024)

typedef __attribute__((ext_vector_type(8))) short bf16x8;
typedef __attribute__((ext_vector_type(4))) float f32x4;

// ---------- helpers ----------
__device__ __forceinline__ u16 f2bf(float f) {
    u32 u = __float_as_uint(f);
    u32 r = (u + 0x7FFFu + ((u >> 16) & 1u)) >> 16;
    return (u16)r;
}
__device__ __forceinline__ float bf2f(u32 bits16) {
    return __uint_as_float(bits16 << 16);
}
__device__ __forceinline__ void gl_lds16(const void* g, void* l) {
    __builtin_amdgcn_global_load_lds(
        (const __attribute__((address_space(1))) u32*)g,
        (__attribute__((address_space(3))) u32*)l, 16, 0, 0);
}

// ---------- graph prep ----------
// zero deg AND the zero-row hs[N_NODES] (gather padding target; re-poisoned each call)
__global__ void zero_kernel(int* __restrict__ deg, int* __restrict__ zrow, int n) {
    int i = blockIdx.x * 256 + threadIdx.x;
    if (i < n) deg[i] = 0;
    if (i < 128) zrow[i] = 0;
}

__global__ void deg_kernel(const int* __restrict__ dst, int* __restrict__ deg, int E) {
    int e = blockIdx.x * 256 + threadIdx.x;
    if (e < E) atomicAdd(&deg[dst[e]], 1);
}

// chunked scan, step 1: inclusive scan within each 1024-chunk + chunk totals
__global__ __launch_bounds__(1024) void scan1_kernel(const int* __restrict__ deg,
                                                     int* __restrict__ partial,
                                                     int* __restrict__ totals, int n) {
    __shared__ int wsum[16];
    __shared__ int woff[16];
    const int tid = threadIdx.x, lane = tid & 63, wid = tid >> 6;
    const int idx = blockIdx.x * 1024 + tid;
    int v = (idx < n) ? deg[idx] : 0;
    int x = v;
#pragma unroll
    for (int off = 1; off < 64; off <<= 1) {
        int t = __shfl_up(x, off, 64);
        if (lane >= off) x += t;
    }
    if (lane == 63) wsum[wid] = x;
    __syncthreads();
    if (tid == 0) {
        int s = 0;
#pragma unroll
        for (int w = 0; w < 16; ++w) { woff[w] = s; s += wsum[w]; }
    }
    __syncthreads();
    x += woff[wid];
    partial[idx] = x;
    if (tid == 1023) totals[blockIdx.x] = x;
}

// step 2: exclusive scan of the 49 chunk totals — one wave, shuffle scan
__global__ void scan2_kernel(const int* __restrict__ totals, int* __restrict__ chunkoff, int nc) {
    const int lane = threadIdx.x & 63;
    int v = (lane < nc) ? totals[lane] : 0;
    int x = v;
#pragma unroll
    for (int off = 1; off < 64; off <<= 1) {
        int t = __shfl_up(x, off, 64);
        if (lane >= off) x += t;
    }
    if (lane < nc) chunkoff[lane] = x - v;
}

// step 3: exclusive row_ptr = chunkoff + inclusive - deg; cursor copy
__global__ void scan3_kernel(const int* __restrict__ deg, const int* __restrict__ partial,
                             const int* __restrict__ chunkoff, int* __restrict__ rptr,
                             int* __restrict__ cursor, int n) {
    int i = blockIdx.x * 256 + threadIdx.x;
    if (i < n) {
        int e = chunkoff[i >> 10] + partial[i] - deg[i];
        rptr[i] = e;
        cursor[i] = e;
    }
    if (i == 0) rptr[n] = N_EDGES;
}

__global__ void fill_kernel(const int* __restrict__ src, const int* __restrict__ dst,
                            int* __restrict__ cursor, int* __restrict__ col, int E) {
    int e = blockIdx.x * 256 + threadIdx.x;
    if (e < E) {
        int p = atomicAdd(&cursor[dst[e]], 1);
        col[p] = src[e];
    }
}

// ---------- fp32 -> bf16 hi/lo split (4 elems/thread) ----------
__global__ void split_kernel(const float* __restrict__ x, u16* __restrict__ hi,
                             u16* __restrict__ lo, int n4) {
    int i = blockIdx.x * 256 + threadIdx.x;
    if (i < n4) {
        float4 v = ((const float4*)x)[i];
        u16 h0 = f2bf(v.x), h1 = f2bf(v.y), h2 = f2bf(v.z), h3 = f2bf(v.w);
        u16 l0 = f2bf(v.x - bf2f(h0)), l1 = f2bf(v.y - bf2f(h1));
        u16 l2 = f2bf(v.z - bf2f(h2)), l3 = f2bf(v.w - bf2f(h3));
        uint2 hv, lv;
        hv.x = (u32)h0 | ((u32)h1 << 16);
        hv.y = (u32)h2 | ((u32)h3 << 16);
        lv.x = (u32)l0 | ((u32)l1 << 16);
        lv.y = (u32)l2 | ((u32)l3 << 16);
        ((uint2*)hi)[i] = hv;
        ((uint2*)lo)[i] = lv;
    }
}

// ---------- W -> W^T hi/lo split. grid (256, 2), block 256 ----------
__global__ void prepw_kernel(const float* __restrict__ W1, const float* __restrict__ W2,
                             u16* __restrict__ h1, u16* __restrict__ l1,
                             u16* __restrict__ h2, u16* __restrict__ l2) {
    int n = blockIdx.x, k = threadIdx.x;
    const float* W = blockIdx.y ? W2 : W1;
    u16* oh = blockIdx.y ? h2 : h1;
    u16* ol = blockIdx.y ? l2 : l1;
    float v = W[k * 256 + n];
    u16 hh = f2bf(v);
    oh[n * 256 + k] = hh;
    ol[n * 256 + k] = f2bf(v - bf2f(hh));
}

// ---------- GEMM: hs = (A @ W) * rsqrt(deg[row]+1), bf16 out ----------
__global__ __launch_bounds__(256) void gemm_split_kernel(
    const u16* __restrict__ Ahi, const u16* __restrict__ Alo,
    const u16* __restrict__ Bthi, const u16* __restrict__ Btlo,
    const int* __restrict__ deg, u16* __restrict__ out, int M) {
    __shared__ u16 Ah[128 * 32];
    __shared__ u16 Al[128 * 32];
    __shared__ u16 Bh[128 * 32];
    __shared__ u16 Bl[128 * 32];
    const int tid = threadIdx.x;
    const int wave = tid >> 6;
    const int lane = tid & 63;
    const int wm = wave >> 1, wn = wave & 1;
    const int quad = lane >> 4, l16 = lane & 15;
    const int m0 = blockIdx.x * 128;
    const int n0 = blockIdx.y * 128;

    f32x4 acc[4][4] = {};

    const int row0 = tid >> 2, row1 = (256 + tid) >> 2;
    const int kk = (tid & 3) * 8;
    int ar0 = m0 + row0; if (ar0 >= M) ar0 = M - 1;
    int ar1 = m0 + row1; if (ar1 >= M) ar1 = M - 1;
    const size_t aoff0 = (size_t)ar0 * 256 + kk;
    const size_t aoff1 = (size_t)ar1 * 256 + kk;
    const size_t boff0 = (size_t)(n0 + row0) * 256 + kk;
    const size_t boff1 = (size_t)(n0 + row1) * 256 + kk;
    const size_t l0 = (size_t)(wave * 64) * 8;
    const size_t l1 = (size_t)(256 + wave * 64) * 8;

    for (int ko = 0; ko < 8; ++ko) {
        const int koff = ko * 32;
        __syncthreads();
        gl_lds16(Ahi + aoff0 + koff, &Ah[l0]);
        gl_lds16(Ahi + aoff1 + koff, &Ah[l1]);
        gl_lds16(Alo + aoff0 + koff, &Al[l0]);
        gl_lds16(Alo + aoff1 + koff, &Al[l1]);
        gl_lds16(Bthi + boff0 + koff, &Bh[l0]);
        gl_lds16(Bthi + boff1 + koff, &Bh[l1]);
        gl_lds16(Btlo + boff0 + koff, &Bl[l0]);
        gl_lds16(Btlo + boff1 + koff, &Bl[l1]);
        asm volatile("s_waitcnt vmcnt(0)" ::: "memory");
        __syncthreads();

        bf16x8 ah[4], al[4], bh[4], bl[4];
#pragma unroll
        for (int mi = 0; mi < 4; ++mi) {
            const int r = (wm * 64 + mi * 16 + l16) * 32 + quad * 8;
            ah[mi] = *(const bf16x8*)&Ah[r];
            al[mi] = *(const bf16x8*)&Al[r];
        }
#pragma unroll
        for (int ni = 0; ni < 4; ++ni) {
            const int r = (wn * 64 + ni * 16 + l16) * 32 + quad * 8;
            bh[ni] = *(const bf16x8*)&Bh[r];
            bl[ni] = *(const bf16x8*)&Bl[r];
        }
#pragma unroll
        for (int mi = 0; mi < 4; ++mi)
#pragma unroll
            for (int ni = 0; ni < 4; ++ni) {
                acc[mi][ni] = __builtin_amdgcn_mfma_f32_16x16x32_bf16(ah[mi], bh[ni], acc[mi][ni], 0, 0, 0);
                acc[mi][ni] = __builtin_amdgcn_mfma_f32_16x16x32_bf16(ah[mi], bl[ni], acc[mi][ni], 0, 0, 0);
                acc[mi][ni] = __builtin_amdgcn_mfma_f32_16x16x32_bf16(al[mi], bh[ni], acc[mi][ni], 0, 0, 0);
            }
    }

#pragma unroll
    for (int mi = 0; mi < 4; ++mi) {
#pragma unroll
        for (int r = 0; r < 4; ++r) {
            int row = m0 + wm * 64 + mi * 16 + quad * 4 + r;
            if (row < M) {
                float s = rsqrtf((float)deg[row] + 1.0f);
#pragma unroll
                for (int ni = 0; ni < 4; ++ni) {
                    int c = n0 + wn * 64 + ni * 16 + l16;
                    out[(size_t)row * 256 + c] = f2bf(acc[mi][ni][r] * s);
                }
            }
        }
    }
}

// ---------- aggregation v3 ----------
// one wave per node. Entry list = [self] + neighbors, padded to x8 with ZROW (hs[Nn] = zeros).
// Lanes 0-31 gather row (entry 2p), lanes 32-63 row (entry 2p+1): 16B/lane dwordx4,
// 2 rows per load. Chunks of 8 entries = 4 loads; next chunk's loads issued before
// accumulating current (8 rows / 4KB in flight). xor-32 shuffle merges half-waves.
__global__ __launch_bounds__(256) void agg_kernel(
    const u16* __restrict__ hs, const int* __restrict__ rptr, const int* __restrict__ cidx,
    const int* __restrict__ deg, const float* __restrict__ bias,
    u16* __restrict__ out_hi, u16* __restrict__ out_lo, float* __restrict__ out_f,
    int mode, int Nn) {
    const int wave = threadIdx.x >> 6, lane = threadIdx.x & 63;
    const int i = blockIdx.x * 4 + wave;
    if (i >= Nn) return;
    const int l32 = lane & 31, half = lane >> 5;
    const int beg = rptr[i], end = rptr[i + 1];
    const int cnt = end - beg;

    int entry = Nn;  // ZROW
    if (lane == 0) entry = i;
    else if (lane - 1 < cnt) entry = cidx[beg + lane - 1];

    int entries = cnt + 1;
    if (entries > 64) entries = 64;
    const int nchunk = (entries + 7) >> 3;
    const size_t lofs = (size_t)l32 * 8;  // 16B per lane within a row

    float a0 = 0, a1 = 0, a2 = 0, a3 = 0, a4 = 0, a5 = 0, a6 = 0, a7 = 0;

#define ISSUE(base, x0, x1, x2, x3)                                             \
    {                                                                           \
        int e0 = __builtin_amdgcn_readlane(entry, (base) + 0);                  \
        int e1 = __builtin_amdgcn_readlane(entry, (base) + 1);                  \
        int e2 = __builtin_amdgcn_readlane(entry, (base) + 2);                  \
        int e3 = __builtin_amdgcn_readlane(entry, (base) + 3);                  \
        int e4 = __builtin_amdgcn_readlane(entry, (base) + 4);                  \
        int e5 = __builtin_amdgcn_readlane(entry, (base) + 5);                  \
        int e6 = __builtin_amdgcn_readlane(entry, (base) + 6);                  \
        int e7 = __builtin_amdgcn_readlane(entry, (base) + 7);                  \
        int p0 = half ? e1 : e0;                                                \
        int p1 = half ? e3 : e2;                                                \
        int p2 = half ? e5 : e4;                                                \
        int p3 = half ? e7 : e6;                                                \
        x0 = *(const uint4*)(hs + (size_t)p0 * 256 + lofs);                     \
        x1 = *(const uint4*)(hs + (size_t)p1 * 256 + lofs);                     \
        x2 = *(const uint4*)(hs + (size_t)p2 * 256 + lofs);                     \
        x3 = *(const uint4*)(hs + (size_t)p3 * 256 + lofs);                     \
    }
#define ACCUM(v)                                                                \
    {                                                                           \
        a0 += bf2f(v.x & 0xffffu); a1 += bf2f(v.x >> 16);                       \
        a2 += bf2f(v.y & 0xffffu); a3 += bf2f(v.y >> 16);                       \
        a4 += bf2f(v.z & 0xffffu); a5 += bf2f(v.z >> 16);                       \
        a6 += bf2f(v.w & 0xffffu); a7 += bf2f(v.w >> 16);                       \
    }

    uint4 va, vb, vc, vd;
    ISSUE(0, va, vb, vc, vd);
    for (int c = 0; c < nchunk; ++c) {
        uint4 na, nb, nc2, nd;
        const bool more = (c + 1 < nchunk);
        if (more) ISSUE((c + 1) * 8, na, nb, nc2, nd);
        ACCUM(va); ACCUM(vb); ACCUM(vc); ACCUM(vd);
        if (more) { va = na; vb = nb; vc = nc2; vd = nd; }
    }
    // rare tail: deg > 63 — both halves load same row; accumulate in half 0 only
    for (int j = beg + 63; j < end; ++j) {
        int s = cidx[j];
        uint4 v = *(const uint4*)(hs + (size_t)s * 256 + lofs);
        if (!half) ACCUM(v);
    }
#undef ISSUE
#undef ACCUM

    // merge half-waves
    a0 += __shfl_xor(a0, 32, 64); a1 += __shfl_xor(a1, 32, 64);
    a2 += __shfl_xor(a2, 32, 64); a3 += __shfl_xor(a3, 32, 64);
    a4 += __shfl_xor(a4, 32, 64); a5 += __shfl_xor(a5, 32, 64);
    a6 += __shfl_xor(a6, 32, 64); a7 += __shfl_xor(a7, 32, 64);

    const float inv = rsqrtf((float)deg[i] + 1.0f);
    const float4 bA = *(const float4*)(bias + l32 * 8);
    const float4 bB = *(const float4*)(bias + l32 * 8 + 4);
    float r0 = fmaxf(fmaf(a0, inv, bA.x), 0.0f);
    float r1 = fmaxf(fmaf(a1, inv, bA.y), 0.0f);
    float r2 = fmaxf(fmaf(a2, inv, bA.z), 0.0f);
    float r3 = fmaxf(fmaf(a3, inv, bA.w), 0.0f);
    float r4 = fmaxf(fmaf(a4, inv, bB.x), 0.0f);
    float r5 = fmaxf(fmaf(a5, inv, bB.y), 0.0f);
    float r6 = fmaxf(fmaf(a6, inv, bB.z), 0.0f);
    float r7 = fmaxf(fmaf(a7, inv, bB.w), 0.0f);

    if (mode == 0) {
        // half 0 writes hi row, half 1 writes lo row (16B per lane, contiguous 512B per half)
        u16 h0 = f2bf(r0), h1 = f2bf(r1), h2 = f2bf(r2), h3 = f2bf(r3);
        u16 h4 = f2bf(r4), h5 = f2bf(r5), h6 = f2bf(r6), h7 = f2bf(r7);
        uint4 w;
        if (!half) {
            w.x = (u32)h0 | ((u32)h1 << 16);
            w.y = (u32)h2 | ((u32)h3 << 16);
            w.z = (u32)h4 | ((u32)h5 << 16);
            w.w = (u32)h6 | ((u32)h7 << 16);
        } else {
            u16 q0 = f2bf(r0 - bf2f(h0)), q1 = f2bf(r1 - bf2f(h1));
            u16 q2 = f2bf(r2 - bf2f(h2)), q3 = f2bf(r3 - bf2f(h3));
            u16 q4 = f2bf(r4 - bf2f(h4)), q5 = f2bf(r5 - bf2f(h5));
            u16 q6 = f2bf(r6 - bf2f(h6)), q7 = f2bf(r7 - bf2f(h7));
            w.x = (u32)q0 | ((u32)q1 << 16);
            w.y = (u32)q2 | ((u32)q3 << 16);
            w.z = (u32)q4 | ((u32)q5 << 16);
            w.w = (u32)q6 | ((u32)q7 << 16);
        }
        u16* dst = half ? out_lo : out_hi;
        *(uint4*)(dst + (size_t)i * 256 + lofs) = w;
    } else {
        // fp32: lane writes 4 cols at 8*l32 + 4*half
        float4 w = half ? make_float4(r4, r5, r6, r7) : make_float4(r0, r1, r2, r3);
        *(float4*)(out_f + (size_t)i * 256 + l32 * 8 + half * 4) = w;
    }
}

extern "C" void kernel_launch(void* const* d_in, const int* in_sizes, int n_in,
                              void* d_out, int out_size, void* d_ws, size_t ws_size,
                              hipStream_t stream) {
    const float* x = (const float*)d_in[0];
    const int* ei = (const int*)d_in[1];  // int32 per harness spec (JAX x64 off)
    const float* W1 = (const float*)d_in[2];
    const float* b1 = (const float*)d_in[3];
    const float* W2 = (const float*)d_in[4];
    const float* b2 = (const float*)d_in[5];
    float* out = (float*)d_out;

    const int Nn = N_NODES, E = N_EDGES;
    const int* srcp = ei;
    const int* dstp = ei + E;

    // d_out doubles as scratch: exactly fits hi+lo bf16 node-feature buffers.
    u16* Ahi = (u16*)d_out;
    u16* Alo = Ahi + (size_t)Nn * DHID;

    // workspace carve (~30 MB total, proven in R2/R3)
    char* p = (char*)d_ws;
    auto take = [&](size_t bytes) -> void* {
        void* r = (void*)p;
        p += (bytes + 255) & ~(size_t)255;
        return r;
    };
    u16* hs      = (u16*)take((size_t)(Nn + 1) * DHID * 2);  // +1 zero row for padding
    int* col     = (int*)take((size_t)E * 4);
    int* deg     = (int*)take((size_t)Nn * 4);
    int* cursor  = (int*)take((size_t)Nn * 4);
    int* rptr    = (int*)take((size_t)(Nn + 1) * 4);
    int* partial = (int*)take((size_t)NCHUNK * 1024 * 4);
    int* totals  = (int*)take(64 * 4);
    int* chunkoff= (int*)take(64 * 4);
    u16* W1t_hi  = (u16*)take(256 * 256 * 2);
    u16* W1t_lo  = (u16*)take(256 * 256 * 2);
    u16* W2t_hi  = (u16*)take(256 * 256 * 2);
    u16* W2t_lo  = (u16*)take(256 * 256 * 2);

    const int nb = (Nn + 255) / 256;
    zero_kernel<<<nb, 256, 0, stream>>>(deg, (int*)(hs + (size_t)Nn * DHID), Nn);
    deg_kernel<<<E / 256, 256, 0, stream>>>(dstp, deg, E);
    scan1_kernel<<<NCHUNK, 1024, 0, stream>>>(deg, partial, totals, Nn);
    scan2_kernel<<<1, 64, 0, stream>>>(totals, chunkoff, NCHUNK);
    scan3_kernel<<<nb, 256, 0, stream>>>(deg, partial, chunkoff, rptr, cursor, Nn);
    fill_kernel<<<E / 256, 256, 0, stream>>>(srcp, dstp, cursor, col, E);

    split_kernel<<<(Nn * DHID / 4 + 255) / 256, 256, 0, stream>>>(x, Ahi, Alo, Nn * DHID / 4);
    prepw_kernel<<<dim3(256, 2), 256, 0, stream>>>(W1, W2, W1t_hi, W1t_lo, W2t_hi, W2t_lo);

    const int gm = (Nn + 127) / 128;  // 391
    // layer 1
    gemm_split_kernel<<<dim3(gm, 2), 256, 0, stream>>>(Ahi, Alo, W1t_hi, W1t_lo, deg, hs, Nn);
    agg_kernel<<<(Nn + 3) / 4, 256, 0, stream>>>(hs, rptr, col, deg, b1, Ahi, Alo, nullptr, 0, Nn);
    // layer 2
    gemm_split_kernel<<<dim3(gm, 2), 256, 0, stream>>>(Ahi, Alo, W2t_hi, W2t_lo, deg, hs, Nn);
    agg_kernel<<<(Nn + 3) / 4, 256, 0, stream>>>(hs, rptr, col, deg, b2, nullptr, nullptr, out, 1, Nn);
}